// Round 2
// baseline (1861.871 us; speedup 1.0000x reference)
//
#include <hip/hip_runtime.h>
#include <cstdint>
#include <cstddef>
#include <math.h>

#define L_ 1024
#define DK_ 64
#define DV_ 64
#define N_ 64
#define H_ 8
#define B_ 8

// readlane broadcast: all lanes get lane `src`'s value of v. src is uniform.
__device__ __forceinline__ float bcast(float v, int src) {
  return __int_as_float(__builtin_amdgcn_readlane(__float_as_int(v), src));
}

// ---------------------------------------------------------------------------
// K1: xm = tril(q_rm @ k^T / 8) written into d_out's attn region.
// v2: float4 LDS reads (stride 68, b128-aligned), strided 4x4 microtile
// (cols tx+16j -> b128 reads spread over all 32 banks, unit-stride C-write),
// float4 staging stores. Zero blocks kept: they ARE the attn output's
// upper-triangle zeros and k2's halo reads.
// ---------------------------------------------------------------------------
__global__ __launch_bounds__(256) void k1_qk_tril(
    const float* __restrict__ qrm, const float* __restrict__ kk,
    float* __restrict__ xm) {
  const int n  = blockIdx.z;
  const int q0 = blockIdx.y * 64;
  const int j0 = blockIdx.x * 64;
  const int t  = threadIdx.x;

  if (j0 > q0) {  // strictly above diagonal: zeros
    const float4 z = make_float4(0.f, 0.f, 0.f, 0.f);
    #pragma unroll
    for (int i = 0; i < 4; ++i) {
      const int row = (t >> 4) + i * 16;
      const int c4  = t & 15;
      float4* p = (float4*)(xm + ((size_t)(n * L_ + q0 + row)) * L_ + j0);
      p[c4] = z;
    }
    return;
  }

  __shared__ float As[64][68];
  __shared__ float Bs[64][68];
  #pragma unroll
  for (int i = 0; i < 4; ++i) {
    const int row = (t >> 4) + i * 16;
    const int c4  = t & 15;
    const float4 a = ((const float4*)(qrm + ((size_t)(n * L_ + q0 + row)) * DK_))[c4];
    const float4 b = ((const float4*)(kk  + ((size_t)(n * L_ + j0 + row)) * DK_))[c4];
    *(float4*)&As[row][c4 * 4] = a;
    *(float4*)&Bs[row][c4 * 4] = b;
  }
  __syncthreads();

  const int ty = t >> 4, tx = t & 15;
  float acc[4][4];
  #pragma unroll
  for (int i = 0; i < 4; ++i)
    #pragma unroll
    for (int j = 0; j < 4; ++j) acc[i][j] = 0.f;

  #pragma unroll
  for (int d0 = 0; d0 < 64; d0 += 4) {
    float4 a4[4], b4[4];
    #pragma unroll
    for (int i = 0; i < 4; ++i) a4[i] = *(const float4*)&As[ty * 4 + i][d0];
    #pragma unroll
    for (int j = 0; j < 4; ++j) b4[j] = *(const float4*)&Bs[tx + 16 * j][d0];
    #pragma unroll
    for (int i = 0; i < 4; ++i)
      #pragma unroll
      for (int j = 0; j < 4; ++j)
        acc[i][j] += a4[i].x * b4[j].x + a4[i].y * b4[j].y +
                     a4[i].z * b4[j].z + a4[i].w * b4[j].w;
  }

  #pragma unroll
  for (int i = 0; i < 4; ++i) {
    const int gq = q0 + ty * 4 + i;
    float* rowp = xm + ((size_t)(n * L_ + gq)) * L_;
    #pragma unroll
    for (int j = 0; j < 4; ++j) {
      const int gj = j0 + tx + 16 * j;  // unit stride across the 16 tx lanes
      rowp[gj] = (gj <= gq) ? acc[i][j] * 0.125f : 0.f;
    }
  }
}

// ---------------------------------------------------------------------------
// K2: xs = relu(conv3x3_{H->H}(xm)) (SAME, zero pad), only where c <= r+4.
// (unchanged this round)
// ---------------------------------------------------------------------------
__global__ __launch_bounds__(256) void k2_conv(
    const float* __restrict__ xm, const float* __restrict__ w,
    float* __restrict__ xs) {
  const int ct = blockIdx.x, rt = blockIdx.y, b = blockIdx.z;
  const int r0 = rt * 4, c0 = ct * 64;
  if (c0 > r0 + 4) return;  // tile entirely outside needed region

  __shared__ float in_s[8][6][68];
  __shared__ float ws[576];
  const int t = threadIdx.x;

  for (int i = t; i < 576; i += 256) ws[i] = w[i];
  for (int e = t; e < 8 * 6 * 66; e += 256) {
    const int hi  = e / 396;
    const int rem = e - hi * 396;
    const int rr  = rem / 66;
    const int cc  = rem - rr * 66;
    const int gr  = r0 - 1 + rr;
    const int gc  = c0 - 1 + cc;
    float v = 0.f;
    if (gr >= 0 && gr < L_ && gc >= 0 && gc < L_)
      v = xm[((size_t)((b * 8 + hi) * L_ + gr)) * L_ + gc];
    in_s[hi][rr][cc] = v;
  }
  __syncthreads();

  const int cc = t & 63;
  const int rr = t >> 6;
  float acc[8];
  #pragma unroll
  for (int ho = 0; ho < 8; ++ho) acc[ho] = 0.f;

  #pragma unroll
  for (int hi = 0; hi < 8; ++hi) {
    float iv[3][3];
    #pragma unroll
    for (int di = 0; di < 3; ++di)
      #pragma unroll
      for (int dj = 0; dj < 3; ++dj)
        iv[di][dj] = in_s[hi][rr + di][cc + dj];
    #pragma unroll
    for (int ho = 0; ho < 8; ++ho) {
      const float* wp = &ws[(ho * 8 + hi) * 9];
      #pragma unroll
      for (int di = 0; di < 3; ++di)
        #pragma unroll
        for (int dj = 0; dj < 3; ++dj)
          acc[ho] += iv[di][dj] * wp[di * 3 + dj];
    }
  }

  const int gr = r0 + rr, gc = c0 + cc;
  #pragma unroll
  for (int ho = 0; ho < 8; ++ho)
    xs[((size_t)((b * 8 + ho) * L_ + gr)) * L_ + gc] = fmaxf(acc[ho], 0.f);
}

// ---------------------------------------------------------------------------
// K3 v3: fused scores + online softmax + attn write + PV.
//  - PER-LANE online (m,l): no cross-lane reduce inside the tile loop; one
//    12-shfl merge per row AFTER the Phase-A loop. (removes 48 serial
//    ds_swizzle ops per tile per wave)
//  - k^T tile at stride 65 (scalar transposed writes/reads conflict-free);
//    v tile at stride 68 (float4 stage writes spread evenly over 32 banks).
//  - Double-buffered LDS, reg prefetch of next tile + epilogue operands,
//    1 barrier/tile, XCD-chunked heavy-first remap (as in v2).
// ---------------------------------------------------------------------------
__global__ __launch_bounds__(256) void k3_fused(
    const float* __restrict__ q, const float* __restrict__ kk,
    const float* __restrict__ v, const float* __restrict__ pre,
    const int* __restrict__ fgp, const float* __restrict__ xs,
    float* attn, float* __restrict__ out) {
  const int bid  = blockIdx.y * gridDim.x + blockIdx.x;  // 4096 wgs
  const int work = (bid & 7) * 512 + (bid >> 3);         // bijective, 8 XCDs
  const int n    = work >> 6;
  const int q0   = (63 - (work & 63)) * 16;

  const int t    = threadIdx.x;
  const int lane = t & 63;
  const int g    = t >> 6;  // wave id 0..3
  const int fg   = *fgp;

  const int srow = t >> 4;  // 0..15 (staging row within 16-row stripe)
  const int c4   = t & 15;

  __shared__ float tbraw[8704];  // 34816 B; kt stride 65, vt stride 68
#define KT(b, d, r) tbraw[(b) * 4160 + (d) * 65 + (r)]
#define VTP(b, c)   (&tbraw[(b) * 4352 + (c) * 68])

  // q held in registers: lane c holds q[n][q0+r_i][c]
  const float* qb = q + ((size_t)(n * L_ + q0)) * DK_;
  float qreg[4];
  #pragma unroll
  for (int i = 0; i < 4; ++i) qreg[i] = qb[(size_t)(g + i * 4) * DK_ + lane];

  float m[4], l[4];
  #pragma unroll
  for (int i = 0; i < 4; ++i) { m[i] = -1e30f; l[i] = 0.f; }

  int r_[4];
  #pragma unroll
  for (int i = 0; i < 4; ++i) r_[i] = q0 + g + i * 4;

  const int ntiles = (q0 >> 6) + 1;
  const float* kbase = kk + (size_t)n * L_ * DK_;

  // ---------------- Phase A prologue: stage k tile 0 (transposed) ---------
  #pragma unroll
  for (int i = 0; i < 4; ++i) {
    const int row = srow + i * 16;
    const float4 kx = *(const float4*)(kbase + (size_t)row * DK_ + c4 * 4);
    KT(0, c4 * 4 + 0, row) = kx.x;
    KT(0, c4 * 4 + 1, row) = kx.y;
    KT(0, c4 * 4 + 2, row) = kx.z;
    KT(0, c4 * 4 + 3, row) = kx.w;
  }
  __syncthreads();

  // ---------------- Phase A: scores + per-lane online (m, l) ----------------
  for (int tile = 0; tile < ntiles; ++tile) {
    const int cur = tile & 1, nxt = cur ^ 1;
    const int j0 = tile * 64;
    const int j  = j0 + lane;
    const bool havenext = (tile + 1) < ntiles;

    // prefetch next k tile into regs (latency hidden under the dot loop)
    float4 kpre[4];
    if (havenext) {
      const float* kb2 = kbase + (size_t)(j0 + 64) * DK_;
      #pragma unroll
      for (int i = 0; i < 4; ++i)
        kpre[i] = *(const float4*)(kb2 + (size_t)(srow + i * 16) * DK_ + c4 * 4);
    }

    // prefetch epilogue operands (coalesced across lanes; predicated on act)
    float rmv[4], prv[4], xsv[4];
    #pragma unroll
    for (int i = 0; i < 4; ++i) {
      const int r = r_[i];
      const bool act = (j <= r);
      rmv[i] = act ? attn[((size_t)(n * L_ + r)) * L_ + j] : 0.f;
      prv[i] = act ? pre[((size_t)(n * L_ + r)) * L_ + j] : 0.f;
      if (fg == 1)
        xsv[i] = (act && r > 0 && j > 0)
                     ? xs[((size_t)(n * L_ + r - 1)) * L_ + (j - 1)] : 0.f;
      else
        xsv[i] = (act && r > 0)
                     ? xs[((size_t)(n * L_ + r - 1)) * L_ + j] : 0.f;
    }

    float dot[4] = {0.f, 0.f, 0.f, 0.f};
    #pragma unroll
    for (int d = 0; d < 64; ++d) {
      const float kd = KT(cur, d, lane);
      #pragma unroll
      for (int i = 0; i < 4; ++i) dot[i] += bcast(qreg[i], d) * kd;
    }

    #pragma unroll
    for (int i = 0; i < 4; ++i) {
      const int r = r_[i];
      float s = -INFINITY;
      if (j <= r) {
        const float sqk = dot[i] * 0.125f;
        const float cnn = (fg == 1)
                              ? ((r == 0 || j == 0) ? rmv[i] : xsv[i])
                              : ((r == 0) ? rmv[i] : xsv[i]);
        const float mixed = cnn * 0.1f + rmv[i] * 0.9f;   // C_MIX
        const float a2    = mixed * 0.4f + sqk * 0.6f;    // B_MIX
        s = prv[i] * 0.1f + a2 * 0.9f;                    // A_MIX
      }
      attn[((size_t)(n * L_ + r)) * L_ + j] = s;  // raw S (or -inf)

      // per-lane online stats (no cross-lane ops; merged once after loop)
      const float mn = fmaxf(m[i], s);
      l[i] = l[i] * __expf(m[i] - mn) + __expf(s - mn);  // s=-inf -> +0
      m[i] = mn;
    }

    // write prefetched k into the other buffer; single barrier per tile
    if (havenext) {
      #pragma unroll
      for (int i = 0; i < 4; ++i) {
        const int row = srow + i * 16;
        KT(nxt, c4 * 4 + 0, row) = kpre[i].x;
        KT(nxt, c4 * 4 + 1, row) = kpre[i].y;
        KT(nxt, c4 * 4 + 2, row) = kpre[i].z;
        KT(nxt, c4 * 4 + 3, row) = kpre[i].w;
      }
    }
    __syncthreads();
  }

  // ---------------- cross-lane merge of (m,l), once per row ----------------
  #pragma unroll
  for (int i = 0; i < 4; ++i) {
    float mf = m[i];
    #pragma unroll
    for (int o = 32; o > 0; o >>= 1) mf = fmaxf(mf, __shfl_xor(mf, o));
    float ls = l[i] * __expf(m[i] - mf);  // m=-1e30 -> 0, l=0 anyway
    #pragma unroll
    for (int o = 32; o > 0; o >>= 1) ls += __shfl_xor(ls, o);
    m[i] = mf;
    l[i] = ls;
  }

  // ---------------- Phase C: normalize + attn write + PV ----------------
  float invl[4];
  #pragma unroll
  for (int i = 0; i < 4; ++i) invl[i] = 1.f / l[i];

  float acc[4] = {0.f, 0.f, 0.f, 0.f};
  const float* vb = v + (size_t)n * L_ * DV_;

  // prologue: stage v tile 0 (straight copy, stride 68) + load S tile 0
  #pragma unroll
  for (int i = 0; i < 4; ++i) {
    const int row = srow + i * 16;
    const float4 vx = *(const float4*)(vb + (size_t)row * DV_ + c4 * 4);
    *(float4*)(VTP(0, row) + c4 * 4) = vx;
  }
  float s_cur[4];
  #pragma unroll
  for (int i = 0; i < 4; ++i)
    s_cur[i] = attn[((size_t)(n * L_ + r_[i])) * L_ + lane];
  __syncthreads();  // also drains Phase A raw-S stores (barrier semantics)

  for (int tile = 0; tile < ntiles; ++tile) {
    const int cur = tile & 1, nxt = cur ^ 1;
    const int j0 = tile * 64;
    const int j  = j0 + lane;
    const bool havenext = (tile + 1) < ntiles;

    // prefetch next v tile + next S stripe (hidden under PV loop)
    float4 vpre[4];
    float s_nxt[4];
    if (havenext) {
      const float* vb2 = vb + (size_t)(j0 + 64) * DV_;
      #pragma unroll
      for (int i = 0; i < 4; ++i)
        vpre[i] = *(const float4*)(vb2 + (size_t)(srow + i * 16) * DV_ + c4 * 4);
      #pragma unroll
      for (int i = 0; i < 4; ++i)
        s_nxt[i] = attn[((size_t)(n * L_ + r_[i])) * L_ + j + 64];
    }

    float p[4];
    #pragma unroll
    for (int i = 0; i < 4; ++i) {
      p[i] = __expf(s_cur[i] - m[i]) * invl[i];  // -inf -> 0
      attn[((size_t)(n * L_ + r_[i])) * L_ + j] = p[i];
    }

    #pragma unroll
    for (int c = 0; c < 64; ++c) {
      const float vv = VTP(cur, c)[lane];
      #pragma unroll
      for (int i = 0; i < 4; ++i) acc[i] += bcast(p[i], c) * vv;
    }

    if (havenext) {
      #pragma unroll
      for (int i = 0; i < 4; ++i) {
        const int row = srow + i * 16;
        *(float4*)(VTP(nxt, row) + c4 * 4) = vpre[i];
      }
      #pragma unroll
      for (int i = 0; i < 4; ++i) s_cur[i] = s_nxt[i];
    }
    __syncthreads();
  }

  #pragma unroll
  for (int i = 0; i < 4; ++i)
    out[((size_t)(n * L_ + r_[i])) * DV_ + lane] = acc[i];
#undef KT
#undef VTP
}

// ---------------------------------------------------------------------------
extern "C" void kernel_launch(void* const* d_in, const int* in_sizes, int n_in,
                              void* d_out, int out_size, void* d_ws,
                              size_t ws_size, hipStream_t stream) {
  const float* q   = (const float*)d_in[0];
  const float* kk  = (const float*)d_in[1];
  const float* v   = (const float*)d_in[2];
  const float* qrm = (const float*)d_in[3];
  const float* pre = (const float*)d_in[4];
  const float* cw  = (const float*)d_in[5];
  // d_in[6] = mask (deterministic causal, computed analytically)
  const int* fg = (const int*)d_in[7];

  float* out  = (float*)d_out;
  float* attn = out + (size_t)N_ * L_ * DV_;  // second output; also rm/S staging
  float* xs   = (float*)d_ws;                 // conv output, N*L*L f32

  k1_qk_tril<<<dim3(16, 16, 64), 256, 0, stream>>>(qrm, kk, attn);
  k2_conv<<<dim3(16, 256, 8), 256, 0, stream>>>(attn, cw, xs);
  k3_fused<<<dim3(64, 64), 256, 0, stream>>>(q, kk, v, pre, fg, xs, attn, out);
}

// Round 3
// 1473.826 us; speedup vs baseline: 1.2633x; 1.2633x over previous
//
#include <hip/hip_runtime.h>
#include <cstdint>
#include <cstddef>
#include <math.h>

#define L_ 1024
#define DK_ 64
#define DV_ 64
#define N_ 64
#define H_ 8
#define B_ 8

// ---------------------------------------------------------------------------
// K1: xm = tril(q_rm @ k^T / 8) written into d_out's attn region.
// (round-1 version restored: scalar LDS reads, 65-stride pads; the float4
// full-unroll variant regressed ~260us)
// ---------------------------------------------------------------------------
__global__ __launch_bounds__(256) void k1_qk_tril(
    const float* __restrict__ qrm, const float* __restrict__ kk,
    float* __restrict__ xm) {
  const int n  = blockIdx.z;
  const int q0 = blockIdx.y * 64;
  const int j0 = blockIdx.x * 64;
  const int t  = threadIdx.x;

  if (j0 > q0) {  // strictly above diagonal: zeros
    const float4 z = make_float4(0.f, 0.f, 0.f, 0.f);
    #pragma unroll
    for (int i = 0; i < 4; ++i) {
      const int row = (t >> 4) + i * 16;
      const int c4  = t & 15;
      float4* p = (float4*)(xm + ((size_t)(n * L_ + q0 + row)) * L_ + j0);
      p[c4] = z;
    }
    return;
  }

  __shared__ float As[64][65];
  __shared__ float Bs[64][65];
  #pragma unroll
  for (int i = 0; i < 4; ++i) {
    const int row = (t >> 4) + i * 16;
    const int c4  = t & 15;
    const float4 a = ((const float4*)(qrm + ((size_t)(n * L_ + q0 + row)) * DK_))[c4];
    const float4 b = ((const float4*)(kk  + ((size_t)(n * L_ + j0 + row)) * DK_))[c4];
    As[row][c4 * 4 + 0] = a.x; As[row][c4 * 4 + 1] = a.y;
    As[row][c4 * 4 + 2] = a.z; As[row][c4 * 4 + 3] = a.w;
    Bs[row][c4 * 4 + 0] = b.x; Bs[row][c4 * 4 + 1] = b.y;
    Bs[row][c4 * 4 + 2] = b.z; Bs[row][c4 * 4 + 3] = b.w;
  }
  __syncthreads();

  const int ty = t >> 4, tx = t & 15;
  float acc[4][4];
  #pragma unroll
  for (int i = 0; i < 4; ++i)
    #pragma unroll
    for (int j = 0; j < 4; ++j) acc[i][j] = 0.f;

  for (int d = 0; d < 64; ++d) {
    float a[4], b[4];
    #pragma unroll
    for (int i = 0; i < 4; ++i) a[i] = As[ty * 4 + i][d];
    #pragma unroll
    for (int j = 0; j < 4; ++j) b[j] = Bs[tx * 4 + j][d];
    #pragma unroll
    for (int i = 0; i < 4; ++i)
      #pragma unroll
      for (int j = 0; j < 4; ++j) acc[i][j] += a[i] * b[j];
  }

  #pragma unroll
  for (int i = 0; i < 4; ++i) {
    const int gq = q0 + ty * 4 + i;
    float* rowp = xm + ((size_t)(n * L_ + gq)) * L_;
    #pragma unroll
    for (int j = 0; j < 4; ++j) {
      const int gj = j0 + tx * 4 + j;
      rowp[gj] = (gj <= gq) ? acc[i][j] * 0.125f : 0.f;
    }
  }
}

// ---------------------------------------------------------------------------
// K2: xs = relu(conv3x3_{H->H}(xm)) (SAME, zero pad), only where c <= r+4.
// (unchanged)
// ---------------------------------------------------------------------------
__global__ __launch_bounds__(256) void k2_conv(
    const float* __restrict__ xm, const float* __restrict__ w,
    float* __restrict__ xs) {
  const int ct = blockIdx.x, rt = blockIdx.y, b = blockIdx.z;
  const int r0 = rt * 4, c0 = ct * 64;
  if (c0 > r0 + 4) return;  // tile entirely outside needed region

  __shared__ float in_s[8][6][68];
  __shared__ float ws[576];
  const int t = threadIdx.x;

  for (int i = t; i < 576; i += 256) ws[i] = w[i];
  for (int e = t; e < 8 * 6 * 66; e += 256) {
    const int hi  = e / 396;
    const int rem = e - hi * 396;
    const int rr  = rem / 66;
    const int cc  = rem - rr * 66;
    const int gr  = r0 - 1 + rr;
    const int gc  = c0 - 1 + cc;
    float v = 0.f;
    if (gr >= 0 && gr < L_ && gc >= 0 && gc < L_)
      v = xm[((size_t)((b * 8 + hi) * L_ + gr)) * L_ + gc];
    in_s[hi][rr][cc] = v;
  }
  __syncthreads();

  const int cc = t & 63;
  const int rr = t >> 6;
  float acc[8];
  #pragma unroll
  for (int ho = 0; ho < 8; ++ho) acc[ho] = 0.f;

  #pragma unroll
  for (int hi = 0; hi < 8; ++hi) {
    float iv[3][3];
    #pragma unroll
    for (int di = 0; di < 3; ++di)
      #pragma unroll
      for (int dj = 0; dj < 3; ++dj)
        iv[di][dj] = in_s[hi][rr + di][cc + dj];
    #pragma unroll
    for (int ho = 0; ho < 8; ++ho) {
      const float* wp = &ws[(ho * 8 + hi) * 9];
      #pragma unroll
      for (int di = 0; di < 3; ++di)
        #pragma unroll
        for (int dj = 0; dj < 3; ++dj)
          acc[ho] += iv[di][dj] * wp[di * 3 + dj];
    }
  }

  const int gr = r0 + rr, gc = c0 + cc;
  #pragma unroll
  for (int ho = 0; ho < 8; ++ho)
    xs[((size_t)((b * 8 + ho) * L_ + gr)) * L_ + gc] = fmaxf(acc[ho], 0.f);
}

// ---------------------------------------------------------------------------
// K3 v4: fused scores + online softmax + attn write + PV.
// Readlane-free inner loops via LDS broadcasts:
//  - q (16 rows) staged once in LDS; dot reads q[r][d0..3] as ONE uniform
//    ds_read_b128 (broadcast) and k[lane][d0..3] as ONE swizzled b128.
//  - k tile row-major [j][d] with XOR group swizzle grp^=(j&15) (required:
//    unswizzled stride-64 rows would camp on 4 banks).
//  - Phase C: p broadcast through a double-buffered LDS stripe (write b32,
//    read back uniform b128); v tile row-major, reads at fixed c are
//    unit-stride conflict-free.
//  - K/V share one 32KB double buffer (phases disjoint); q/p share 8KB.
//  - Keeps: double-buffer + reg prefetch, 1 barrier/tile, per-lane online
//    (m,l) merged once, XCD-chunked heavy-first remap.
// ---------------------------------------------------------------------------
__global__ __launch_bounds__(256) void k3_fused(
    const float* __restrict__ q, const float* __restrict__ kk,
    const float* __restrict__ v, const float* __restrict__ pre,
    const int* __restrict__ fgp, const float* __restrict__ xs,
    float* attn, float* __restrict__ out) {
  const int bid  = blockIdx.y * gridDim.x + blockIdx.x;  // 4096 wgs
  const int work = (bid & 7) * 512 + (bid >> 3);         // bijective, 8 XCDs
  const int n    = work >> 6;
  const int q0   = (63 - (work & 63)) * 16;

  const int t    = threadIdx.x;
  const int lane = t & 63;
  const int g    = t >> 6;  // wave id 0..3
  const int fg   = *fgp;

  const int srow = t >> 4;  // 0..15 (staging row within 16-row stripe)
  const int c4   = t & 15;

  __shared__ float tiles[2][64][64];  // Phase A: k (swizzled); Phase C: v
  __shared__ float qps[2][16][64];    // Phase A: qps[0]=q; Phase C: ps dbuf

  int r_[4], lr_[4];
  #pragma unroll
  for (int i = 0; i < 4; ++i) { r_[i] = q0 + g + i * 4; lr_[i] = g + i * 4; }
  size_t rowoff[4];
  #pragma unroll
  for (int i = 0; i < 4; ++i) rowoff[i] = ((size_t)(n * L_ + r_[i])) * L_;

  const int ntiles = (q0 >> 6) + 1;
  const float* kbase = kk + (size_t)n * L_ * DK_;
  const int wswz = (c4 ^ srow) << 2;  // staging write swizzle ((row&15)==srow)
  const int lx = lane & 15;

  // ---------------- Phase A prologue: stage q rows + k tile 0 -------------
  {
    const float4 qx =
        *(const float4*)(q + ((size_t)(n * L_ + q0 + srow)) * DK_ + c4 * 4);
    *(float4*)&qps[0][srow][c4 * 4] = qx;
  }
  #pragma unroll
  for (int i = 0; i < 4; ++i) {
    const int row = srow + i * 16;
    const float4 kx = *(const float4*)(kbase + (size_t)row * DK_ + c4 * 4);
    *(float4*)&tiles[0][row][wswz] = kx;
  }
  __syncthreads();

  float m[4], l[4];
  #pragma unroll
  for (int i = 0; i < 4; ++i) { m[i] = -1e30f; l[i] = 0.f; }

  // ---------------- Phase A: scores + per-lane online (m, l) --------------
  for (int tile = 0; tile < ntiles; ++tile) {
    const int cur = tile & 1, nxt = cur ^ 1;
    const int j0 = tile * 64;
    const int j  = j0 + lane;
    const bool havenext = (tile + 1) < ntiles;

    // prefetch next k tile into regs (latency hidden under the dot loop)
    float4 kpre[4];
    if (havenext) {
      const float* kb2 = kbase + (size_t)(j0 + 64) * DK_;
      #pragma unroll
      for (int i = 0; i < 4; ++i)
        kpre[i] = *(const float4*)(kb2 + (size_t)(srow + i * 16) * DK_ + c4 * 4);
    }

    // prefetch epilogue operands
    float rmv[4], prv[4], xsv[4];
    #pragma unroll
    for (int i = 0; i < 4; ++i) {
      const int r = r_[i];
      const bool act = (j <= r);
      rmv[i] = act ? attn[rowoff[i] + j] : 0.f;
      prv[i] = act ? pre[rowoff[i] + j] : 0.f;
      if (fg == 1)
        xsv[i] = (act && r > 0 && j > 0)
                     ? xs[rowoff[i] - L_ + (j - 1)] : 0.f;
      else
        xsv[i] = (act && r > 0) ? xs[rowoff[i] - L_ + j] : 0.f;
    }

    // dot: k via swizzled per-lane b128, q via uniform (broadcast) b128
    float dot[4] = {0.f, 0.f, 0.f, 0.f};
    const float* krow = &tiles[cur][0][0] + lane * 64;
    #pragma unroll 4
    for (int gg = 0; gg < 16; ++gg) {
      const float4 kq = *(const float4*)(krow + ((gg ^ lx) << 2));
      #pragma unroll
      for (int i = 0; i < 4; ++i) {
        const float4 q4 = *(const float4*)&qps[0][lr_[i]][gg << 2];
        dot[i] += q4.x * kq.x + q4.y * kq.y + q4.z * kq.z + q4.w * kq.w;
      }
    }

    #pragma unroll
    for (int i = 0; i < 4; ++i) {
      const int r = r_[i];
      float s = -INFINITY;
      if (j <= r) {
        const float sqk = dot[i] * 0.125f;
        const float cnn = (fg == 1)
                              ? ((r == 0 || j == 0) ? rmv[i] : xsv[i])
                              : ((r == 0) ? rmv[i] : xsv[i]);
        const float mixed = cnn * 0.1f + rmv[i] * 0.9f;   // C_MIX
        const float a2    = mixed * 0.4f + sqk * 0.6f;    // B_MIX
        s = prv[i] * 0.1f + a2 * 0.9f;                    // A_MIX
      }
      attn[rowoff[i] + j] = s;  // raw S (or -inf)

      const float mn = fmaxf(m[i], s);
      l[i] = l[i] * __expf(m[i] - mn) + __expf(s - mn);  // s=-inf -> +0
      m[i] = mn;
    }

    if (havenext) {
      #pragma unroll
      for (int i = 0; i < 4; ++i) {
        const int row = srow + i * 16;
        *(float4*)&tiles[nxt][row][wswz] = kpre[i];
      }
    }
    __syncthreads();
  }

  // ---------------- cross-lane merge of (m,l), once per row ----------------
  #pragma unroll
  for (int i = 0; i < 4; ++i) {
    float mf = m[i];
    #pragma unroll
    for (int o = 32; o > 0; o >>= 1) mf = fmaxf(mf, __shfl_xor(mf, o));
    float ls = l[i] * __expf(m[i] - mf);
    #pragma unroll
    for (int o = 32; o > 0; o >>= 1) ls += __shfl_xor(ls, o);
    m[i] = mf;
    l[i] = ls;
  }

  float invl[4];
  #pragma unroll
  for (int i = 0; i < 4; ++i) invl[i] = 1.f / l[i];

  // ---------------- Phase C prologue: stage v0 + p0 -----------------------
  float acc[4] = {0.f, 0.f, 0.f, 0.f};
  const float* vb = v + (size_t)n * L_ * DV_;

  #pragma unroll
  for (int i = 0; i < 4; ++i) {
    const int row = srow + i * 16;
    const float4 vx = *(const float4*)(vb + (size_t)row * DV_ + c4 * 4);
    *(float4*)&tiles[0][row][c4 * 4] = vx;  // linear (reads are per-c rows)
  }
  #pragma unroll
  for (int i = 0; i < 4; ++i) {
    const float s  = attn[rowoff[i] + lane];
    const float pv = __expf(s - m[i]) * invl[i];  // -inf -> 0
    qps[0][lr_[i]][lane] = pv;
    attn[rowoff[i] + lane] = pv;
  }
  __syncthreads();

  // ---------------- Phase C: PV via LDS p-broadcast -----------------------
  for (int tile = 0; tile < ntiles; ++tile) {
    const int cur = tile & 1, nxt = cur ^ 1;
    const int j0 = tile * 64;
    const bool havenext = (tile + 1) < ntiles;

    // prefetch next v tile + next S stripe
    float4 vpre[4];
    float s_nxt[4];
    if (havenext) {
      const float* vb2 = vb + (size_t)(j0 + 64) * DV_;
      #pragma unroll
      for (int i = 0; i < 4; ++i)
        vpre[i] = *(const float4*)(vb2 + (size_t)(srow + i * 16) * DV_ + c4 * 4);
      #pragma unroll
      for (int i = 0; i < 4; ++i)
        s_nxt[i] = attn[rowoff[i] + j0 + 64 + lane];
    }

    // PV: v per-lane b32 (unit-stride rows), p uniform b128
    #pragma unroll 4
    for (int cs = 0; cs < 16; ++cs) {
      const int c0 = cs * 4;
      const float v0 = tiles[cur][c0 + 0][lane];
      const float v1 = tiles[cur][c0 + 1][lane];
      const float v2 = tiles[cur][c0 + 2][lane];
      const float v3 = tiles[cur][c0 + 3][lane];
      #pragma unroll
      for (int i = 0; i < 4; ++i) {
        const float4 pr = *(const float4*)&qps[cur][lr_[i]][c0];
        acc[i] += pr.x * v0 + pr.y * v1 + pr.z * v2 + pr.w * v3;
      }
    }

    if (havenext) {
      #pragma unroll
      for (int i = 0; i < 4; ++i) {
        const int row = srow + i * 16;
        *(float4*)&tiles[nxt][row][c4 * 4] = vpre[i];
      }
      #pragma unroll
      for (int i = 0; i < 4; ++i) {
        const float pv = __expf(s_nxt[i] - m[i]) * invl[i];
        qps[nxt][lr_[i]][lane] = pv;
        attn[rowoff[i] + j0 + 64 + lane] = pv;
      }
    }
    __syncthreads();
  }

  #pragma unroll
  for (int i = 0; i < 4; ++i)
    out[((size_t)(n * L_ + r_[i])) * DV_ + lane] = acc[i];
}

// ---------------------------------------------------------------------------
extern "C" void kernel_launch(void* const* d_in, const int* in_sizes, int n_in,
                              void* d_out, int out_size, void* d_ws,
                              size_t ws_size, hipStream_t stream) {
  const float* q   = (const float*)d_in[0];
  const float* kk  = (const float*)d_in[1];
  const float* v   = (const float*)d_in[2];
  const float* qrm = (const float*)d_in[3];
  const float* pre = (const float*)d_in[4];
  const float* cw  = (const float*)d_in[5];
  // d_in[6] = mask (deterministic causal, computed analytically)
  const int* fg = (const int*)d_in[7];

  float* out  = (float*)d_out;
  float* attn = out + (size_t)N_ * L_ * DV_;  // second output; also rm/S staging
  float* xs   = (float*)d_ws;                 // conv output, N*L*L f32

  k1_qk_tril<<<dim3(16, 16, 64), 256, 0, stream>>>(qrm, kk, attn);
  k2_conv<<<dim3(16, 256, 8), 256, 0, stream>>>(attn, cw, xs);
  k3_fused<<<dim3(64, 64), 256, 0, stream>>>(q, kk, v, pre, fg, xs, attn, out);
}

// Round 4
// 1444.465 us; speedup vs baseline: 1.2890x; 1.0203x over previous
//
#include <hip/hip_runtime.h>
#include <cstdint>
#include <cstddef>
#include <math.h>

#define L_ 1024
#define DK_ 64
#define DV_ 64
#define N_ 64
#define H_ 8
#define B_ 8

// ---------------------------------------------------------------------------
// K1 v3: xm = tril(q_rm @ k^T / 8) into d_out's attn region.
// 128x128 tile, 256 threads, 8x8 microtile with STRIDED maps:
//   rows = ty16 + 16*ii  (4 consecutive rows per wave -> conflict-free b128)
//   cols = tx  + 16*jj   (2-way bank alias only)
// 16:1 fma:ds_read ratio (was 2:1). acc statically indexed. d-loop unroll 2.
// Zero blocks (bx>by) write the attn output's upper-triangle zeros.
// ---------------------------------------------------------------------------
__global__ __launch_bounds__(256) void k1_qk_tril(
    const float* __restrict__ qrm, const float* __restrict__ kk,
    float* __restrict__ xm) {
  const int n  = blockIdx.z;
  const int by = blockIdx.y, bx = blockIdx.x;
  const int q0 = by * 128, j0 = bx * 128;
  const int t  = threadIdx.x;

  if (bx > by) {  // strictly above diagonal: zeros
    const float4 z = make_float4(0.f, 0.f, 0.f, 0.f);
    #pragma unroll
    for (int i = 0; i < 16; ++i) {
      const int idx = t + i * 256;  // 0..4095 over 128 rows x 32 f4
      const int row = idx >> 5, c4 = idx & 31;
      *(float4*)(xm + ((size_t)(n * L_ + q0 + row)) * L_ + j0 + c4 * 4) = z;
    }
    return;
  }

  __shared__ float As[128][68];
  __shared__ float Bs[128][68];
  #pragma unroll
  for (int i = 0; i < 8; ++i) {
    const int idx = t + i * 256;  // 0..2047 over 128 rows x 16 f4
    const int row = idx >> 4, c4 = idx & 15;
    *(float4*)&As[row][c4 * 4] =
        *(const float4*)(qrm + ((size_t)(n * L_ + q0 + row)) * DK_ + c4 * 4);
    *(float4*)&Bs[row][c4 * 4] =
        *(const float4*)(kk + ((size_t)(n * L_ + j0 + row)) * DK_ + c4 * 4);
  }
  __syncthreads();

  const int ty16 = t >> 4;  // 0..15
  const int tx   = t & 15;  // 0..15

  float acc[8][8];
  #pragma unroll
  for (int ii = 0; ii < 8; ++ii)
    #pragma unroll
    for (int jj = 0; jj < 8; ++jj) acc[ii][jj] = 0.f;

  #pragma unroll 2
  for (int d0 = 0; d0 < 64; d0 += 4) {
    float4 b4[8];
    #pragma unroll
    for (int jj = 0; jj < 8; ++jj)
      b4[jj] = *(const float4*)&Bs[tx + 16 * jj][d0];
    #pragma unroll
    for (int ii = 0; ii < 8; ++ii) {
      const float4 a4 = *(const float4*)&As[ty16 + 16 * ii][d0];
      #pragma unroll
      for (int jj = 0; jj < 8; ++jj)
        acc[ii][jj] += a4.x * b4[jj].x + a4.y * b4[jj].y +
                       a4.z * b4[jj].z + a4.w * b4[jj].w;
    }
  }

  #pragma unroll
  for (int ii = 0; ii < 8; ++ii) {
    const int gq = q0 + ty16 + 16 * ii;
    float* rowp = xm + ((size_t)(n * L_ + gq)) * L_;
    #pragma unroll
    for (int jj = 0; jj < 8; ++jj) {
      const int gj = j0 + tx + 16 * jj;
      rowp[gj] = (gj <= gq) ? acc[ii][jj] * 0.125f : 0.f;
    }
  }
}

// ---------------------------------------------------------------------------
// K2 v2: xs = relu(conv3x3_{H->H}(xm)) (SAME, zero pad), only where c<=r+4.
// Staging rewritten: float4 halo loads of an ALIGNED 72-col window
// (c0-4 .. c0+67): every 16B segment is fully in-range or fully out, so no
// partial bounds handling; 4 staging iterations instead of 13 scalar ones.
// ---------------------------------------------------------------------------
__global__ __launch_bounds__(256) void k2_conv(
    const float* __restrict__ xm, const float* __restrict__ w,
    float* __restrict__ xs) {
  const int ct = blockIdx.x, rt = blockIdx.y, b = blockIdx.z;
  const int r0 = rt * 4, c0 = ct * 64;
  if (c0 > r0 + 4) return;  // tile entirely outside needed region

  __shared__ float in_s[8][6][76];  // 72 cols staged, stride 76
  __shared__ float ws[576];
  const int t = threadIdx.x;

  for (int i = t; i < 576; i += 256) ws[i] = w[i];

  // stage: 8ch x 6rows x 18 float4 = 864 segments
  #pragma unroll
  for (int i = 0; i < 4; ++i) {
    const int e = t + i * 256;
    if (e < 864) {
      const int ch  = e / 108;
      const int rem = e - ch * 108;
      const int row = rem / 18;
      const int f4  = rem - row * 18;
      const int gr  = r0 - 1 + row;
      const int gc  = c0 - 4 + f4 * 4;
      float4 val = make_float4(0.f, 0.f, 0.f, 0.f);
      if (gr >= 0 && gr < L_ && gc >= 0 && gc <= L_ - 4)
        val = *(const float4*)(xm + ((size_t)((b * 8 + ch) * L_ + gr)) * L_ + gc);
      *(float4*)&in_s[ch][row][f4 * 4] = val;
    }
  }
  __syncthreads();

  const int cc = t & 63;
  const int rr = t >> 6;
  float acc[8];
  #pragma unroll
  for (int ho = 0; ho < 8; ++ho) acc[ho] = 0.f;

  #pragma unroll
  for (int hi = 0; hi < 8; ++hi) {
    float iv[3][3];
    #pragma unroll
    for (int di = 0; di < 3; ++di)
      #pragma unroll
      for (int dj = 0; dj < 3; ++dj)
        iv[di][dj] = in_s[hi][rr + di][cc + 3 + dj];  // local col of cc is cc+4
    #pragma unroll
    for (int ho = 0; ho < 8; ++ho) {
      const float* wp = &ws[(ho * 8 + hi) * 9];
      #pragma unroll
      for (int di = 0; di < 3; ++di)
        #pragma unroll
        for (int dj = 0; dj < 3; ++dj)
          acc[ho] += iv[di][dj] * wp[di * 3 + dj];
    }
  }

  const int gr = r0 + rr, gc = c0 + cc;
  #pragma unroll
  for (int ho = 0; ho < 8; ++ho)
    xs[((size_t)((b * 8 + ho) * L_ + gr)) * L_ + gc] = fmaxf(acc[ho], 0.f);
}

// ---------------------------------------------------------------------------
// K3 v5: as v4, but Phase C iterates tiles in REVERSE order so the S values
// written last in Phase A (still L2-resident) are re-read first -> cuts the
// S round-trip HBM traffic that appeared when occupancy doubled.
// ---------------------------------------------------------------------------
__global__ __launch_bounds__(256) void k3_fused(
    const float* __restrict__ q, const float* __restrict__ kk,
    const float* __restrict__ v, const float* __restrict__ pre,
    const int* __restrict__ fgp, const float* __restrict__ xs,
    float* attn, float* __restrict__ out) {
  const int bid  = blockIdx.y * gridDim.x + blockIdx.x;  // 4096 wgs
  const int work = (bid & 7) * 512 + (bid >> 3);         // bijective, 8 XCDs
  const int n    = work >> 6;
  const int q0   = (63 - (work & 63)) * 16;

  const int t    = threadIdx.x;
  const int lane = t & 63;
  const int g    = t >> 6;  // wave id 0..3
  const int fg   = *fgp;

  const int srow = t >> 4;  // 0..15 (staging row within 16-row stripe)
  const int c4   = t & 15;

  __shared__ float tiles[2][64][64];  // Phase A: k (swizzled); Phase C: v
  __shared__ float qps[2][16][64];    // Phase A: qps[0]=q; Phase C: ps dbuf

  int r_[4], lr_[4];
  #pragma unroll
  for (int i = 0; i < 4; ++i) { r_[i] = q0 + g + i * 4; lr_[i] = g + i * 4; }
  size_t rowoff[4];
  #pragma unroll
  for (int i = 0; i < 4; ++i) rowoff[i] = ((size_t)(n * L_ + r_[i])) * L_;

  const int ntiles = (q0 >> 6) + 1;
  const float* kbase = kk + (size_t)n * L_ * DK_;
  const int wswz = (c4 ^ srow) << 2;  // staging write swizzle
  const int lx = lane & 15;

  // ---------------- Phase A prologue: stage q rows + k tile 0 -------------
  {
    const float4 qx =
        *(const float4*)(q + ((size_t)(n * L_ + q0 + srow)) * DK_ + c4 * 4);
    *(float4*)&qps[0][srow][c4 * 4] = qx;
  }
  #pragma unroll
  for (int i = 0; i < 4; ++i) {
    const int row = srow + i * 16;
    const float4 kx = *(const float4*)(kbase + (size_t)row * DK_ + c4 * 4);
    *(float4*)&tiles[0][row][wswz] = kx;
  }
  __syncthreads();

  float m[4], l[4];
  #pragma unroll
  for (int i = 0; i < 4; ++i) { m[i] = -1e30f; l[i] = 0.f; }

  // ---------------- Phase A: scores + per-lane online (m, l) --------------
  for (int tile = 0; tile < ntiles; ++tile) {
    const int cur = tile & 1, nxt = cur ^ 1;
    const int j0 = tile * 64;
    const int j  = j0 + lane;
    const bool havenext = (tile + 1) < ntiles;

    // prefetch next k tile into regs (latency hidden under the dot loop)
    float4 kpre[4];
    if (havenext) {
      const float* kb2 = kbase + (size_t)(j0 + 64) * DK_;
      #pragma unroll
      for (int i = 0; i < 4; ++i)
        kpre[i] = *(const float4*)(kb2 + (size_t)(srow + i * 16) * DK_ + c4 * 4);
    }

    // prefetch epilogue operands
    float rmv[4], prv[4], xsv[4];
    #pragma unroll
    for (int i = 0; i < 4; ++i) {
      const int r = r_[i];
      const bool act = (j <= r);
      rmv[i] = act ? attn[rowoff[i] + j] : 0.f;
      prv[i] = act ? pre[rowoff[i] + j] : 0.f;
      if (fg == 1)
        xsv[i] = (act && r > 0 && j > 0)
                     ? xs[rowoff[i] - L_ + (j - 1)] : 0.f;
      else
        xsv[i] = (act && r > 0) ? xs[rowoff[i] - L_ + j] : 0.f;
    }

    // dot: k via swizzled per-lane b128, q via uniform (broadcast) b128
    float dot[4] = {0.f, 0.f, 0.f, 0.f};
    const float* krow = &tiles[cur][0][0] + lane * 64;
    #pragma unroll 4
    for (int gg = 0; gg < 16; ++gg) {
      const float4 kq = *(const float4*)(krow + ((gg ^ lx) << 2));
      #pragma unroll
      for (int i = 0; i < 4; ++i) {
        const float4 q4 = *(const float4*)&qps[0][lr_[i]][gg << 2];
        dot[i] += q4.x * kq.x + q4.y * kq.y + q4.z * kq.z + q4.w * kq.w;
      }
    }

    #pragma unroll
    for (int i = 0; i < 4; ++i) {
      const int r = r_[i];
      float s = -INFINITY;
      if (j <= r) {
        const float sqk = dot[i] * 0.125f;
        const float cnn = (fg == 1)
                              ? ((r == 0 || j == 0) ? rmv[i] : xsv[i])
                              : ((r == 0) ? rmv[i] : xsv[i]);
        const float mixed = cnn * 0.1f + rmv[i] * 0.9f;   // C_MIX
        const float a2    = mixed * 0.4f + sqk * 0.6f;    // B_MIX
        s = prv[i] * 0.1f + a2 * 0.9f;                    // A_MIX
      }
      attn[rowoff[i] + j] = s;  // raw S (or -inf)

      const float mn = fmaxf(m[i], s);
      l[i] = l[i] * __expf(m[i] - mn) + __expf(s - mn);  // s=-inf -> +0
      m[i] = mn;
    }

    if (havenext) {
      #pragma unroll
      for (int i = 0; i < 4; ++i) {
        const int row = srow + i * 16;
        *(float4*)&tiles[nxt][row][wswz] = kpre[i];
      }
    }
    __syncthreads();
  }

  // ---------------- cross-lane merge of (m,l), once per row ----------------
  #pragma unroll
  for (int i = 0; i < 4; ++i) {
    float mf = m[i];
    #pragma unroll
    for (int o = 32; o > 0; o >>= 1) mf = fmaxf(mf, __shfl_xor(mf, o));
    float ls = l[i] * __expf(m[i] - mf);
    #pragma unroll
    for (int o = 32; o > 0; o >>= 1) ls += __shfl_xor(ls, o);
    m[i] = mf;
    l[i] = ls;
  }

  float invl[4];
  #pragma unroll
  for (int i = 0; i < 4; ++i) invl[i] = 1.f / l[i];

  // ---------------- Phase C prologue: stage v/p of LAST tile --------------
  // (reverse order: last-written S is still L2-hot)
  float acc[4] = {0.f, 0.f, 0.f, 0.f};
  const float* vb = v + (size_t)n * L_ * DV_;
  const int jlast = (ntiles - 1) * 64;

  #pragma unroll
  for (int i = 0; i < 4; ++i) {
    const int row = srow + i * 16;
    const float4 vx =
        *(const float4*)(vb + (size_t)(jlast + row) * DV_ + c4 * 4);
    *(float4*)&tiles[0][row][c4 * 4] = vx;  // linear (reads are per-c rows)
  }
  #pragma unroll
  for (int i = 0; i < 4; ++i) {
    const float s  = attn[rowoff[i] + jlast + lane];
    const float pv = __expf(s - m[i]) * invl[i];  // -inf -> 0
    qps[0][lr_[i]][lane] = pv;
    attn[rowoff[i] + jlast + lane] = pv;
  }
  __syncthreads();

  // ---------------- Phase C: PV via LDS p-broadcast (reverse tiles) -------
  for (int it = 0; it < ntiles; ++it) {
    const int cur = it & 1, nxt = cur ^ 1;
    const int j0 = (ntiles - 1 - it) * 64;
    const bool havenext = (it + 1) < ntiles;

    // prefetch previous v tile + previous S stripe
    float4 vpre[4];
    float s_nxt[4];
    if (havenext) {
      const float* vb2 = vb + (size_t)(j0 - 64) * DV_;
      #pragma unroll
      for (int i = 0; i < 4; ++i)
        vpre[i] = *(const float4*)(vb2 + (size_t)(srow + i * 16) * DV_ + c4 * 4);
      #pragma unroll
      for (int i = 0; i < 4; ++i)
        s_nxt[i] = attn[rowoff[i] + j0 - 64 + lane];
    }

    // PV: v per-lane b32 (unit-stride rows), p uniform b128
    #pragma unroll 4
    for (int cs = 0; cs < 16; ++cs) {
      const int c0 = cs * 4;
      const float v0 = tiles[cur][c0 + 0][lane];
      const float v1 = tiles[cur][c0 + 1][lane];
      const float v2 = tiles[cur][c0 + 2][lane];
      const float v3 = tiles[cur][c0 + 3][lane];
      #pragma unroll
      for (int i = 0; i < 4; ++i) {
        const float4 pr = *(const float4*)&qps[cur][lr_[i]][c0];
        acc[i] += pr.x * v0 + pr.y * v1 + pr.z * v2 + pr.w * v3;
      }
    }

    if (havenext) {
      #pragma unroll
      for (int i = 0; i < 4; ++i) {
        const int row = srow + i * 16;
        *(float4*)&tiles[nxt][row][c4 * 4] = vpre[i];
      }
      #pragma unroll
      for (int i = 0; i < 4; ++i) {
        const float pv = __expf(s_nxt[i] - m[i]) * invl[i];
        qps[nxt][lr_[i]][lane] = pv;
        attn[rowoff[i] + j0 - 64 + lane] = pv;
      }
    }
    __syncthreads();
  }

  #pragma unroll
  for (int i = 0; i < 4; ++i)
    out[((size_t)(n * L_ + r_[i])) * DV_ + lane] = acc[i];
}

// ---------------------------------------------------------------------------
extern "C" void kernel_launch(void* const* d_in, const int* in_sizes, int n_in,
                              void* d_out, int out_size, void* d_ws,
                              size_t ws_size, hipStream_t stream) {
  const float* q   = (const float*)d_in[0];
  const float* kk  = (const float*)d_in[1];
  const float* v   = (const float*)d_in[2];
  const float* qrm = (const float*)d_in[3];
  const float* pre = (const float*)d_in[4];
  const float* cw  = (const float*)d_in[5];
  // d_in[6] = mask (deterministic causal, computed analytically)
  const int* fg = (const int*)d_in[7];

  float* out  = (float*)d_out;
  float* attn = out + (size_t)N_ * L_ * DV_;  // second output; also rm/S staging
  float* xs   = (float*)d_ws;                 // conv output, N*L*L f32

  k1_qk_tril<<<dim3(8, 8, 64), 256, 0, stream>>>(qrm, kk, attn);
  k2_conv<<<dim3(16, 256, 8), 256, 0, stream>>>(attn, cw, xs);
  k3_fused<<<dim3(64, 64), 256, 0, stream>>>(q, kk, v, pre, fg, xs, attn, out);
}